// Round 2
// baseline (363.223 us; speedup 1.0000x reference)
//
#include <hip/hip_runtime.h>
#include <math.h>
#include <stdint.h>

#define N_NODE 100000
#define N_EDGE 1000000
#define DIM    64
#define NB     256
#define NVOCAB 401
#define SCAN_B 1024
#define NCHUNK ((N_NODE + SCAN_B - 1) / SCAN_B)
#define AGG_WAVES 8192
#define NSHARD 32
#define DEG_E (N_EDGE / NSHARD)     // 31250 edges per deg block (exact)

typedef short short8  __attribute__((ext_vector_type(8)));
typedef float floatx4 __attribute__((ext_vector_type(4)));
typedef unsigned short ushort_t;

__device__ inline unsigned short f2bf_rne(float f)
{
    unsigned u = __float_as_uint(f);
    unsigned r = u + 0x7FFF + ((u >> 16) & 1);
    return (unsigned short)(r >> 16);
}
__device__ inline float bflo(unsigned u) { return __uint_as_float(u << 16); }
__device__ inline float bfhi(unsigned u) { return __uint_as_float(u & 0xFFFF0000u); }
__device__ inline unsigned short f2h(float f)
{
    _Float16 h = (_Float16)f;
    unsigned short s; __builtin_memcpy(&s, &h, 2); return s;
}
__device__ inline float h2f(unsigned b)
{
    unsigned short s = (unsigned short)b;
    _Float16 h; __builtin_memcpy(&h, &s, 2); return (float)h;
}

__device__ inline void split8(float4 v0, float4 v1, short8& hi, short8& lo)
{
    float f[8] = {v0.x, v0.y, v0.z, v0.w, v1.x, v1.y, v1.z, v1.w};
    #pragma unroll
    for (int j = 0; j < 8; ++j) {
        unsigned u = __float_as_uint(f[j]);
        unsigned r = u + 0x7FFF + ((u >> 16) & 1);
        unsigned short h = (unsigned short)(r >> 16);
        float hf = __uint_as_float(((unsigned)h) << 16);
        float l  = f[j] - hf;
        unsigned u2 = __float_as_uint(l);
        unsigned r2 = u2 + 0x7FFF + ((u2 >> 16) & 1);
        hi[j] = (short)h;
        lo[j] = (short)(r2 >> 16);
    }
}

// ---------------------------------------------------------------------------
// init: pre-split the 4 weight matrices into bf16 hi/lo tables.
// wsp layout: [w][2][4096] bf16, w: 0=Ws 1=Wr 2=Wqr 3=Wh.
// (deg counters are now zeroed by their owning prep block.)
// ---------------------------------------------------------------------------
#define INIT_GRID ((4 * 4096 + 255) / 256)

__global__ __launch_bounds__(256) void init_kernel(
    const float* __restrict__ Ws, const float* __restrict__ Wr,
    const float* __restrict__ Wqr, const float* __restrict__ Wh,
    ushort_t* __restrict__ wsp)
{
    int tid = blockIdx.x * 256 + threadIdx.x;
    if (tid < 4 * 4096) {
        int w = tid >> 12, e = tid & 4095;
        const float* src = (w == 0) ? Ws : (w == 1) ? Wr : (w == 2) ? Wqr : Wh;
        float f = src[e];
        unsigned u = __float_as_uint(f);
        unsigned r = u + 0x7FFF + ((u >> 16) & 1);
        unsigned short h = (unsigned short)(r >> 16);
        float hf = __uint_as_float(((unsigned)h) << 16);
        float l  = f - hf;
        unsigned u2 = __float_as_uint(l);
        unsigned r2 = u2 + 0x7FFF + ((u2 >> 16) & 1);
        wsp[w * 8192 + e]        = h;
        wsp[w * 8192 + 4096 + e] = (unsigned short)(r2 >> 16);
    }
}

// ---------------------------------------------------------------------------
// gemm64p body (fp32 A, PRE-SPLIT bf16 W): Y[r][:] = act( X[idx?idx[r]:r] @ W^T + b ).
// Swapped operands: lane holds 4 consecutive output cols -> packed stores.
// out_mode: 0 fp32 | 1 fp32+relu | 2 bf16 | 3 bf16 + bf16(X) copy to Y2.
// ---------------------------------------------------------------------------
__device__ void gemm64p_body(
    const float* __restrict__ X,
    const int*   __restrict__ idx,
    const ushort_t* __restrict__ Whi,   // [64][64] bf16
    const ushort_t* __restrict__ Wlo,   // [64][64] bf16
    const float* __restrict__ bias,
    void* __restrict__ Yv,
    ushort_t* __restrict__ Y2,
    int R, int out_mode, int blk)
{
    int wave = threadIdx.x >> 6;
    int lane = threadIdx.x & 63;
    int m    = lane & 15;
    int quad = lane >> 4;
    int r0   = blk * 64 + wave * 16;

    int r = r0 + m;
    int src = (r < R) ? (idx ? idx[r] : r) : 0;
    const float* xrow = X + (size_t)src * DIM + quad * 8;

    float4 a0[2], a1[2];
    #pragma unroll
    for (int c = 0; c < 2; ++c) {
        a0[c] = *(const float4*)(xrow + 32 * c);
        a1[c] = *(const float4*)(xrow + 32 * c + 4);
    }
    short8 ah[2], al[2];
    #pragma unroll
    for (int c = 0; c < 2; ++c) split8(a0[c], a1[c], ah[c], al[c]);

    if (out_mode == 3 && r < R) {
        #pragma unroll
        for (int c = 0; c < 2; ++c)
            *(short8*)(Y2 + (size_t)r * DIM + 32 * c + quad * 8) = ah[c];
    }

    floatx4 acc[4] = {{0,0,0,0},{0,0,0,0},{0,0,0,0},{0,0,0,0}};
    #pragma unroll
    for (int g = 0; g < 4; ++g) {
        const ushort_t* whrow = Whi + (size_t)(g * 16 + m) * DIM + quad * 8;
        const ushort_t* wlrow = Wlo + (size_t)(g * 16 + m) * DIM + quad * 8;
        #pragma unroll
        for (int c = 0; c < 2; ++c) {
            short8 bh = *(const short8*)(whrow + 32 * c);
            short8 bl = *(const short8*)(wlrow + 32 * c);
            acc[g] = __builtin_amdgcn_mfma_f32_16x16x32_bf16(bh, ah[c], acc[g], 0, 0, 0);
            acc[g] = __builtin_amdgcn_mfma_f32_16x16x32_bf16(bl, ah[c], acc[g], 0, 0, 0);
            acc[g] = __builtin_amdgcn_mfma_f32_16x16x32_bf16(bh, al[c], acc[g], 0, 0, 0);
        }
    }

    if (r < R) {
        #pragma unroll
        for (int g = 0; g < 4; ++g) {
            float4 bv = make_float4(0.f, 0.f, 0.f, 0.f);
            if (bias) bv = *(const float4*)(bias + g * 16 + quad * 4);
            float v0 = acc[g][0] + bv.x;
            float v1 = acc[g][1] + bv.y;
            float v2 = acc[g][2] + bv.z;
            float v3 = acc[g][3] + bv.w;
            if (out_mode == 1) {
                v0 = fmaxf(v0, 0.f); v1 = fmaxf(v1, 0.f);
                v2 = fmaxf(v2, 0.f); v3 = fmaxf(v3, 0.f);
            }
            if (out_mode >= 2) {
                uint2 o;
                o.x = (unsigned)f2bf_rne(v0) | ((unsigned)f2bf_rne(v1) << 16);
                o.y = (unsigned)f2bf_rne(v2) | ((unsigned)f2bf_rne(v3) << 16);
                *(uint2*)((ushort_t*)Yv + (size_t)r * DIM + g * 16 + quad * 4) = o;
            } else {
                *(float4*)((float*)Yv + (size_t)r * DIM + g * 16 + quad * 4) =
                    make_float4(v0, v1, v2, v3);
            }
        }
    }
}

// ---------------------------------------------------------------------------
// Final gemm, bf16 A, pre-split W: Y[r] = relu( A[r] @ W^T ), fp32 out.
// ---------------------------------------------------------------------------
__global__ __launch_bounds__(256) void gemm64p_bf16A_kernel(
    const ushort_t* __restrict__ A,
    const ushort_t* __restrict__ Whi,
    const ushort_t* __restrict__ Wlo,
    float* __restrict__ Y, int R)
{
    int wave = threadIdx.x >> 6;
    int lane = threadIdx.x & 63;
    int m    = lane & 15;
    int quad = lane >> 4;
    int r0   = blockIdx.x * 64 + wave * 16;

    int r = r0 + m;
    int src = (r < R) ? r : 0;
    short8 a8[2];
    #pragma unroll
    for (int c = 0; c < 2; ++c)
        a8[c] = *(const short8*)(A + (size_t)src * DIM + 32 * c + quad * 8);

    floatx4 acc[4] = {{0,0,0,0},{0,0,0,0},{0,0,0,0},{0,0,0,0}};
    #pragma unroll
    for (int g = 0; g < 4; ++g) {
        const ushort_t* whrow = Whi + (size_t)(g * 16 + m) * DIM + quad * 8;
        const ushort_t* wlrow = Wlo + (size_t)(g * 16 + m) * DIM + quad * 8;
        #pragma unroll
        for (int c = 0; c < 2; ++c) {
            short8 bh = *(const short8*)(whrow + 32 * c);
            short8 bl = *(const short8*)(wlrow + 32 * c);
            acc[g] = __builtin_amdgcn_mfma_f32_16x16x32_bf16(bh, a8[c], acc[g], 0, 0, 0);
            acc[g] = __builtin_amdgcn_mfma_f32_16x16x32_bf16(bl, a8[c], acc[g], 0, 0, 0);
        }
    }

    if (r < R) {
        #pragma unroll
        for (int g = 0; g < 4; ++g) {
            *(float4*)(Y + (size_t)r * DIM + g * 16 + quad * 4) =
                make_float4(fmaxf(acc[g][0], 0.f), fmaxf(acc[g][1], 0.f),
                            fmaxf(acc[g][2], 0.f), fmaxf(acc[g][3], 0.f));
        }
    }
}

// ---------------------------------------------------------------------------
// OLD fp32-W gemm body (fallback path only).
// ---------------------------------------------------------------------------
__device__ void gemm64_body(
    const float* __restrict__ X,
    const int*   __restrict__ idx,
    const float* __restrict__ W,
    const float* __restrict__ bias,
    void* __restrict__ Yv,
    ushort_t* __restrict__ Y2,
    int R, int out_mode, int blk)
{
    int wave = threadIdx.x >> 6;
    int lane = threadIdx.x & 63;
    int m    = lane & 15;
    int quad = lane >> 4;
    int r0   = blk * 64 + wave * 16;

    int r = r0 + m;
    int src = (r < R) ? (idx ? idx[r] : r) : 0;
    const float* xrow = X + (size_t)src * DIM + quad * 8;

    float4 a0[2], a1[2];
    #pragma unroll
    for (int c = 0; c < 2; ++c) {
        a0[c] = *(const float4*)(xrow + 32 * c);
        a1[c] = *(const float4*)(xrow + 32 * c + 4);
    }
    short8 ah[2], al[2];
    #pragma unroll
    for (int c = 0; c < 2; ++c) split8(a0[c], a1[c], ah[c], al[c]);

    if (out_mode == 3 && r < R) {
        #pragma unroll
        for (int c = 0; c < 2; ++c)
            *(short8*)(Y2 + (size_t)r * DIM + 32 * c + quad * 8) = ah[c];
    }

    floatx4 acc[4] = {{0,0,0,0},{0,0,0,0},{0,0,0,0},{0,0,0,0}};
    #pragma unroll
    for (int g = 0; g < 4; ++g) {
        const float* wrow = W + (size_t)(g * 16 + m) * DIM + quad * 8;
        #pragma unroll
        for (int c = 0; c < 2; ++c) {
            float4 b0 = *(const float4*)(wrow + 32 * c);
            float4 b1 = *(const float4*)(wrow + 32 * c + 4);
            short8 bh, bl;
            split8(b0, b1, bh, bl);
            acc[g] = __builtin_amdgcn_mfma_f32_16x16x32_bf16(ah[c], bh, acc[g], 0, 0, 0);
            acc[g] = __builtin_amdgcn_mfma_f32_16x16x32_bf16(ah[c], bl, acc[g], 0, 0, 0);
            acc[g] = __builtin_amdgcn_mfma_f32_16x16x32_bf16(al[c], bh, acc[g], 0, 0, 0);
        }
    }

    #pragma unroll
    for (int g = 0; g < 4; ++g) {
        float bv = bias ? bias[g * 16 + m] : 0.0f;
        #pragma unroll
        for (int reg = 0; reg < 4; ++reg) {
            int rr = r0 + quad * 4 + reg;
            if (rr < R) {
                float v = acc[g][reg] + bv;
                if (out_mode == 1) v = fmaxf(v, 0.0f);
                if (out_mode >= 2)
                    ((ushort_t*)Yv)[(size_t)rr * DIM + g * 16 + m] = f2bf_rne(v);
                else
                    ((float*)Yv)[(size_t)rr * DIM + g * 16 + m] = v;
            }
        }
    }
}

__global__ __launch_bounds__(256) void gemm64_kernel(
    const float* __restrict__ X, const int* __restrict__ idx,
    const float* __restrict__ W, const float* __restrict__ bias,
    void* __restrict__ Yv, ushort_t* __restrict__ Y2, int R, int out_mode)
{
    gemm64_body(X, idx, W, bias, Yv, Y2, R, out_mode, blockIdx.x);
}

// ---------------------------------------------------------------------------
// prep: ONE launch.
// Blocks 0..31: deg/rank/epack. Each block OWNS shard b (contiguous 31250
// edges): zeroes its private deg[] slice, then counts with WORKGROUP-scope
// atomics -> RMW executes in the local XCD L2 instead of Infinity Fabric
// (per-XCD L2s are non-coherent, so agent-scope atomics always go out to
// the memory side; that fabric RMW throughput was the whole 57us).
// Blocks 32..42: small rel/qr gemms. Rest: hsWs gemm.
// ---------------------------------------------------------------------------
#define G1 ((N_NODE + 63) / 64)            // 1563
#define G2 ((NVOCAB + 63) / 64)            // 7
#define G3 (NB / 64)                       // 4
#define GSMALL (G2 + G3)                   // 11
#define PREP_GRID (NSHARD + GSMALL + G1)

__global__ __launch_bounds__(256) void prep_kernel(
    const float* __restrict__ hidden,
    const float* __restrict__ rela,
    const int*   __restrict__ q_rel,
    const ushort_t* __restrict__ wsp,   // pre-split weights
    const float* __restrict__ Wqr_b,
    ushort_t* __restrict__ hsWs,
    ushort_t* __restrict__ hidb,
    ushort_t* __restrict__ rel_preb,
    ushort_t* __restrict__ relab,
    ushort_t* __restrict__ qr_preb,
    const int* __restrict__ edges,
    int* __restrict__ deg8,        // [NSHARD][N_NODE], zeroed by owner block
    int* __restrict__ rank,
    int2* __restrict__ epack)
{
    int b = blockIdx.x;
    if (b < NSHARD) {
        int* mydeg = deg8 + (size_t)b * N_NODE;
        // zero own shard (int4-vectorized; N_NODE % 4 == 0)
        for (int g = threadIdx.x * 4; g < N_NODE; g += 256 * 4)
            *(int4*)(mydeg + g) = make_int4(0, 0, 0, 0);
        __syncthreads();
        int base = b * DEG_E;
        for (int e0i = 0; e0i < DEG_E; e0i += 2048) {
            #pragma unroll
            for (int k = 0; k < 8; ++k) {
                int off = e0i + k * 256 + threadIdx.x;
                if (off < DEG_E) {
                    int e = base + off;
                    int2 ab = *(const int2*)(edges + (size_t)e * 6);      // (r_idx,0)
                    int2 cd = *(const int2*)(edges + (size_t)e * 6 + 2);  // (rel,0)
                    int2 ef = *(const int2*)(edges + (size_t)e * 6 + 4);  // (sub,obj)
                    epack[e] = make_int2(ef.x | (cd.x << 17), ef.y | (ab.x << 17));
                    rank[e] = __hip_atomic_fetch_add(&mydeg[ef.y], 1,
                                  __ATOMIC_RELAXED, __HIP_MEMORY_SCOPE_WORKGROUP);
                }
            }
        }
    } else if (b < NSHARD + G2) {
        gemm64p_body(rela, nullptr, wsp + 1 * 8192, wsp + 1 * 8192 + 4096,
                     nullptr, rel_preb, relab, NVOCAB, 3, b - NSHARD);
    } else if (b < NSHARD + GSMALL) {
        gemm64p_body(rela, q_rel, wsp + 2 * 8192, wsp + 2 * 8192 + 4096,
                     Wqr_b, qr_preb, nullptr, NB, 2, b - NSHARD - G2);
    } else {
        gemm64p_body(hidden, nullptr, wsp, wsp + 4096,
                     nullptr, hsWs, hidb, N_NODE, 3, b - NSHARD - GSMALL);
    }
}

// ---------------------------------------------------------------------------
// CSR scan pipeline over sharded counters.
// ---------------------------------------------------------------------------
__global__ __launch_bounds__(SCAN_B) void scan1_kernel(const int* __restrict__ deg8,
                                                       int* __restrict__ partial)
{
    __shared__ int s[SCAN_B];
    int g = blockIdx.x * SCAN_B + threadIdx.x;
    int tot = 0;
    if (g < N_NODE)
        #pragma unroll
        for (int k = 0; k < NSHARD; ++k) tot += deg8[(size_t)k * N_NODE + g];
    s[threadIdx.x] = tot;
    __syncthreads();
    for (int off = SCAN_B / 2; off; off >>= 1) {
        if (threadIdx.x < off) s[threadIdx.x] += s[threadIdx.x + off];
        __syncthreads();
    }
    if (threadIdx.x == 0) partial[blockIdx.x] = s[0];
}

__global__ __launch_bounds__(128) void scan2_kernel(int* __restrict__ partial, int n)
{
    __shared__ int s[128];
    int t = threadIdx.x;
    int v = (t < n) ? partial[t] : 0;
    s[t] = v;
    __syncthreads();
    for (int off = 1; off < 128; off <<= 1) {
        int add = (t >= off) ? s[t - off] : 0;
        __syncthreads();
        s[t] += add;
        __syncthreads();
    }
    if (t < n) partial[t] = s[t] - v;   // exclusive
}

// scan3: offs[g+1] = global inclusive; rewrites deg8 in place into per-shard
// slot bases: deg8[s][g] <- offs[g] + sum_{s'<s} deg_s'(g).
__global__ __launch_bounds__(SCAN_B) void scan3_kernel(int* __restrict__ deg8,
                                                       const int* __restrict__ partial,
                                                       int* __restrict__ offs)
{
    __shared__ int s[SCAN_B];
    int g = blockIdx.x * SCAN_B + threadIdx.x;
    int d[NSHARD];
    int tot = 0;
    if (g < N_NODE) {
        #pragma unroll
        for (int k = 0; k < NSHARD; ++k) { d[k] = deg8[(size_t)k * N_NODE + g]; tot += d[k]; }
    }
    s[threadIdx.x] = tot;
    __syncthreads();
    for (int off = 1; off < SCAN_B; off <<= 1) {
        int add = ((int)threadIdx.x >= off) ? s[threadIdx.x - off] : 0;
        __syncthreads();
        s[threadIdx.x] += add;
        __syncthreads();
    }
    if (g < N_NODE) {
        int incl = partial[blockIdx.x] + s[threadIdx.x];
        offs[g + 1] = incl;
        if (g == 0) offs[0] = 0;
        int run = incl - tot;                     // = offs[g]
        #pragma unroll
        for (int k = 0; k < NSHARD; ++k) { deg8[(size_t)k * N_NODE + g] = run; run += d[k]; }
    }
}

// ---------------------------------------------------------------------------
// alpha + scatter: reads only epack (8B coalesced) + rank + bf16 tables.
// Quarter-wave, 4 edges/quarter, 64 edges/block. slot = base8[shard][obj]+rank.
// shard = e / DEG_E (edge ranges are contiguous per deg block now).
// ---------------------------------------------------------------------------
__global__ __launch_bounds__(256) void alpha_scatter_kernel(
    const int2*     __restrict__ epack,
    const int*      __restrict__ rank,
    const int*      __restrict__ base8,     // deg8 transformed by scan3
    const ushort_t* __restrict__ hsWs,
    const ushort_t* __restrict__ rel_preb,
    const ushort_t* __restrict__ qr_preb,
    const float*    __restrict__ wattn,
    int2*           __restrict__ csr2)
{
    int tid = blockIdx.x * 256 + threadIdx.x;
    if (tid < 4) csr2[N_EDGE + tid] = make_int2(0, 0);

    int wave = threadIdx.x >> 6;
    int lane = threadIdx.x & 63;
    int q    = lane >> 4;
    int l    = lane & 15;
    int f0   = l * 4;
    int e0   = (blockIdx.x * 4 + wave) * 16 + q * 4;

    float4 wa = *(const float4*)(wattn + f0);

    int   sub[4], rl[4], ob[4];
    float t[4];
    #pragma unroll
    for (int j = 0; j < 4; ++j) {
        int e = e0 + j;
        int2 ep = epack[e];
        sub[j] = ep.x & 0x1FFFF;
        rl[j]  = (int)((unsigned)ep.x >> 17);
        ob[j]  = ep.y & 0x1FFFF;
        int ri = (int)((unsigned)ep.y >> 17);

        uint2 uh = *(const uint2*)(hsWs     + (size_t)sub[j] * DIM + f0);
        uint2 ur = *(const uint2*)(rel_preb + (size_t)rl[j]  * DIM + f0);
        uint2 uq = *(const uint2*)(qr_preb  + (size_t)ri     * DIM + f0);

        float tt =  fmaxf(bflo(uh.x) + bflo(ur.x) + bflo(uq.x), 0.f) * wa.x;
        tt = fmaf(fmaxf(bfhi(uh.x) + bfhi(ur.x) + bfhi(uq.x), 0.f), wa.y, tt);
        tt = fmaf(fmaxf(bflo(uh.y) + bflo(ur.y) + bflo(uq.y), 0.f), wa.z, tt);
        tt = fmaf(fmaxf(bfhi(uh.y) + bfhi(ur.y) + bfhi(uq.y), 0.f), wa.w, tt);
        t[j] = tt;
    }
    #pragma unroll
    for (int j = 0; j < 4; ++j) {
        t[j] += __shfl_xor(t[j], 1);
        t[j] += __shfl_xor(t[j], 2);
        t[j] += __shfl_xor(t[j], 4);
        t[j] += __shfl_xor(t[j], 8);
    }

    if (l < 4) {
        int j = l;
        int e = e0 + j;
        int sh = (int)((unsigned)e / (unsigned)DEG_E);
        float alpha = 1.0f / (1.0f + __expf(-t[j]));
        int slot = base8[(size_t)sh * N_NODE + ob[j]] + rank[e];
        csr2[slot] = make_int2(sub[j],
            (int)(((unsigned)rl[j] << 16) | f2h(alpha)));
    }
}

// ---------------------------------------------------------------------------
// Aggregation: persistent waves, 8 edges/iter, bf16 output.
// ---------------------------------------------------------------------------
__global__ __launch_bounds__(256) void agg_kernel(
    const int2*     __restrict__ csr2,
    const int*      __restrict__ offs,
    const ushort_t* __restrict__ hB,
    const ushort_t* __restrict__ relab,
    ushort_t* __restrict__ aggb)         // bf16 [N_NODE][64]
{
    int lane = threadIdx.x & 63;
    int q    = lane >> 4;
    int l    = lane & 15;
    int f0   = l * 4;
    int wv = __builtin_amdgcn_readfirstlane((blockIdx.x * blockDim.x + threadIdx.x) >> 6);

    int i   = offs[wv];
    int end = offs[wv + 1];
    for (int n = wv; n < N_NODE; n += AGG_WAVES) {
        int nn = n + AGG_WAVES;
        int ni = 0, ne = 0;
        if (nn < N_NODE) { ni = offs[nn]; ne = offs[nn + 1]; }

        float4 acc = make_float4(0.f, 0.f, 0.f, 0.f);
        int2 e0 = csr2[min(i + q,     N_EDGE + 3)];
        int2 e1 = csr2[min(i + 4 + q, N_EDGE + 3)];
        while (i < end) {
            int2 f0e = csr2[min(i + 8 + q,  N_EDGE + 3)];
            int2 f1e = csr2[min(i + 12 + q, N_EDGE + 3)];
            float v0 = (i + q < end)     ? 1.0f : 0.0f;
            float v1 = (i + 4 + q < end) ? 1.0f : 0.0f;

            unsigned ey0 = (unsigned)e0.y, ey1 = (unsigned)e1.y;
            float al0 = v0 * h2f(ey0 & 0xFFFFu);
            float al1 = v1 * h2f(ey1 & 0xFFFFu);

            uint2 uh0 = *(const uint2*)(hB    + (size_t)e0.x        * DIM + f0);
            uint2 ur0 = *(const uint2*)(relab + (size_t)(ey0 >> 16) * DIM + f0);
            uint2 uh1 = *(const uint2*)(hB    + (size_t)e1.x        * DIM + f0);
            uint2 ur1 = *(const uint2*)(relab + (size_t)(ey1 >> 16) * DIM + f0);

            acc.x = fmaf(al0, bflo(uh0.x) + bflo(ur0.x), acc.x);
            acc.y = fmaf(al0, bfhi(uh0.x) + bfhi(ur0.x), acc.y);
            acc.z = fmaf(al0, bflo(uh0.y) + bflo(ur0.y), acc.z);
            acc.w = fmaf(al0, bfhi(uh0.y) + bfhi(ur0.y), acc.w);
            acc.x = fmaf(al1, bflo(uh1.x) + bflo(ur1.x), acc.x);
            acc.y = fmaf(al1, bfhi(uh1.x) + bfhi(ur1.x), acc.y);
            acc.z = fmaf(al1, bflo(uh1.y) + bflo(ur1.y), acc.z);
            acc.w = fmaf(al1, bfhi(uh1.y) + bfhi(ur1.y), acc.w);

            e0 = f0e; e1 = f1e;
            i += 8;
        }

        acc.x += __shfl_xor(acc.x, 16); acc.x += __shfl_xor(acc.x, 32);
        acc.y += __shfl_xor(acc.y, 16); acc.y += __shfl_xor(acc.y, 32);
        acc.z += __shfl_xor(acc.z, 16); acc.z += __shfl_xor(acc.z, 32);
        acc.w += __shfl_xor(acc.w, 16); acc.w += __shfl_xor(acc.w, 32);
        if (q == 0) {
            uint2 o;
            o.x = (unsigned)f2bf_rne(acc.x) | ((unsigned)f2bf_rne(acc.y) << 16);
            o.y = (unsigned)f2bf_rne(acc.z) | ((unsigned)f2bf_rne(acc.w) << 16);
            *(uint2*)(aggb + (size_t)n * DIM + f0) = o;
        }

        i = ni; end = ne;
    }
}

// ---------------------------------------------------------------------------
// Fallback (ws too small): wave-per-edge atomic kernel, bf16 tables.
// ---------------------------------------------------------------------------
__global__ __launch_bounds__(256) void edge_kernel(
    const int*      __restrict__ edges,
    const ushort_t* __restrict__ hB,
    const ushort_t* __restrict__ relab,
    const ushort_t* __restrict__ hsWs,
    const ushort_t* __restrict__ rel_preb,
    const ushort_t* __restrict__ qr_preb,
    const float*    __restrict__ wattn,
    float* __restrict__ out)
{
    int e = (blockIdx.x * blockDim.x + threadIdx.x) >> 6;
    if (e >= N_EDGE) return;
    int lane = threadIdx.x & 63;
    int r_i = edges[e * 6 + 0];
    int rl  = edges[e * 6 + 2];
    int sb  = edges[e * 6 + 4];
    int ob  = edges[e * 6 + 5];
    float hs = __uint_as_float(((unsigned)hB[(size_t)sb * DIM + lane]) << 16);
    float hr = __uint_as_float(((unsigned)relab[(size_t)rl * DIM + lane]) << 16);
    float p1 = __uint_as_float(((unsigned)hsWs[(size_t)sb * DIM + lane]) << 16);
    float p2 = __uint_as_float(((unsigned)rel_preb[(size_t)rl * DIM + lane]) << 16);
    float p3 = __uint_as_float(((unsigned)qr_preb[(size_t)r_i * DIM + lane]) << 16);
    float t = wattn[lane] * fmaxf(p1 + p2 + p3, 0.0f);
    #pragma unroll
    for (int off = 32; off; off >>= 1) t += __shfl_xor(t, off);
    float alpha = 1.0f / (1.0f + __expf(-t));
    atomicAdd(&out[(size_t)ob * DIM + lane], (hs + hr) * alpha);
}

extern "C" void kernel_launch(void* const* d_in, const int* in_sizes, int n_in,
                              void* d_out, int out_size, void* d_ws, size_t ws_size,
                              hipStream_t stream)
{
    const float* hidden = (const float*)d_in[0];
    const int*   q_rel  = (const int*)  d_in[1];
    const int*   edges  = (const int*)  d_in[2];
    const float* rela   = (const float*)d_in[3];
    const float* Ws     = (const float*)d_in[4];
    const float* Wr     = (const float*)d_in[5];
    const float* Wqr    = (const float*)d_in[6];
    const float* Wqr_b  = (const float*)d_in[7];
    const float* Wattn  = (const float*)d_in[8];
    const float* Wh     = (const float*)d_in[9];
    float* out = (float*)d_out;

    // ---- workspace layout ----
    ushort_t* qr_preb  = (ushort_t*)d_ws;                 // 256*64 bf16
    ushort_t* rel_preb = qr_preb + NB * DIM;              // 401*64 bf16
    ushort_t* relab    = rel_preb + NVOCAB * DIM;         // 401*64 bf16
    ushort_t* hsWs     = relab + NVOCAB * DIM;            // 100000*64 bf16
    ushort_t* hidb     = hsWs + (size_t)N_NODE * DIM;     // 100000*64 bf16
    int2* epack  = (int2*)(((uintptr_t)(hidb + (size_t)N_NODE * DIM) + 15) & ~(uintptr_t)15);
    int*  rank   = (int*)(epack + N_EDGE);                // N_EDGE
    int*  deg8   = rank + N_EDGE;                         // NSHARD*N_NODE
    int*  offs   = deg8 + (size_t)NSHARD * N_NODE;        // N_NODE+1
    int*  partial= offs + (N_NODE + 1);                   // 128
    int2* csr2   = (int2*)(((uintptr_t)(partial + 128) + 15) & ~(uintptr_t)15);
    ushort_t* wsp = (ushort_t*)(csr2 + N_EDGE + 4);       // 4*2*4096 bf16 (64KB)
    size_t csr_need = ((char*)(wsp + 4 * 8192)) - (char*)d_ws;
    bool use_csr = ws_size >= csr_need;
    // aggb aliases the dead epack/rank/deg8 region (24.8MB >= 12.8MB needed);
    // epack/rank/deg8 are dead after alpha_scatter; csr2/offs/wsp stay intact.
    ushort_t* aggb = (ushort_t*)epack;

    if (use_csr) {
        init_kernel<<<INIT_GRID, 256, 0, stream>>>(Ws, Wr, Wqr, Wh, wsp);
        prep_kernel<<<PREP_GRID, 256, 0, stream>>>(
            hidden, rela, q_rel, wsp, Wqr_b,
            hsWs, hidb, rel_preb, relab, qr_preb, edges, deg8, rank, epack);
        scan1_kernel<<<NCHUNK, SCAN_B, 0, stream>>>(deg8, partial);
        scan2_kernel<<<1, 128, 0, stream>>>(partial, NCHUNK);
        scan3_kernel<<<NCHUNK, SCAN_B, 0, stream>>>(deg8, partial, offs);
        alpha_scatter_kernel<<<N_EDGE / 64, 256, 0, stream>>>(
            epack, rank, deg8, hsWs, rel_preb, qr_preb, Wattn, csr2);
        agg_kernel<<<AGG_WAVES / 4, 256, 0, stream>>>(csr2, offs, hidb, relab, aggb);
        gemm64p_bf16A_kernel<<<(N_NODE + 63) / 64, 256, 0, stream>>>(
            aggb, wsp + 3 * 8192, wsp + 3 * 8192 + 4096, out, N_NODE);
    } else {
        gemm64_kernel<<<(NVOCAB + 63) / 64, 256, 0, stream>>>(
            rela, nullptr, Wr, nullptr, rel_preb, relab, NVOCAB, 3);
        gemm64_kernel<<<(NB + 63) / 64, 256, 0, stream>>>(
            rela, q_rel, Wqr, Wqr_b, qr_preb, nullptr, NB, 2);
        gemm64_kernel<<<(N_NODE + 63) / 64, 256, 0, stream>>>(
            hidden, nullptr, Ws, nullptr, hsWs, hidb, N_NODE, 3);
        hipMemsetAsync(d_out, 0, (size_t)N_NODE * DIM * sizeof(float), stream);
        edge_kernel<<<(N_EDGE + 3) / 4, 256, 0, stream>>>(
            edges, hidb, relab, hsWs, rel_preb, qr_preb, Wattn, out);
        gemm64_kernel<<<(N_NODE + 63) / 64, 256, 0, stream>>>(
            out, nullptr, Wh, nullptr, out, nullptr, N_NODE, 1);
    }
}

// Round 3
// 270.750 us; speedup vs baseline: 1.3415x; 1.3415x over previous
//
#include <hip/hip_runtime.h>
#include <math.h>
#include <stdint.h>

#define N_NODE 100000
#define N_EDGE 1000000
#define DIM    64
#define NB     256
#define NVOCAB 401
#define SCAN_B 1024
#define NCHUNK ((N_NODE + SCAN_B - 1) / SCAN_B)
#define AGG_WAVES 8192
#define NSHARD 8
#define EPB 2048            // edges per deg block (256 thr x 8)

typedef short short8  __attribute__((ext_vector_type(8)));
typedef float floatx4 __attribute__((ext_vector_type(4)));
typedef unsigned short ushort_t;

__device__ inline unsigned short f2bf_rne(float f)
{
    unsigned u = __float_as_uint(f);
    unsigned r = u + 0x7FFF + ((u >> 16) & 1);
    return (unsigned short)(r >> 16);
}
__device__ inline float bflo(unsigned u) { return __uint_as_float(u << 16); }
__device__ inline float bfhi(unsigned u) { return __uint_as_float(u & 0xFFFF0000u); }
__device__ inline unsigned short f2h(float f)
{
    _Float16 h = (_Float16)f;
    unsigned short s; __builtin_memcpy(&s, &h, 2); return s;
}
__device__ inline float h2f(unsigned b)
{
    unsigned short s = (unsigned short)b;
    _Float16 h; __builtin_memcpy(&h, &s, 2); return (float)h;
}

__device__ inline void split8(float4 v0, float4 v1, short8& hi, short8& lo)
{
    float f[8] = {v0.x, v0.y, v0.z, v0.w, v1.x, v1.y, v1.z, v1.w};
    #pragma unroll
    for (int j = 0; j < 8; ++j) {
        unsigned u = __float_as_uint(f[j]);
        unsigned r = u + 0x7FFF + ((u >> 16) & 1);
        unsigned short h = (unsigned short)(r >> 16);
        float hf = __uint_as_float(((unsigned)h) << 16);
        float l  = f[j] - hf;
        unsigned u2 = __float_as_uint(l);
        unsigned r2 = u2 + 0x7FFF + ((u2 >> 16) & 1);
        hi[j] = (short)h;
        lo[j] = (short)(r2 >> 16);
    }
}

// ---------------------------------------------------------------------------
// init: zero deg8 AND pre-split the 4 weight matrices into bf16 hi/lo tables.
// wsp layout: [w][2][4096] bf16, w: 0=Ws 1=Wr 2=Wqr 3=Wh.
// ---------------------------------------------------------------------------
#define INIT_GRID ((NSHARD * N_NODE + 255) / 256)

__global__ __launch_bounds__(256) void init_kernel(
    const float* __restrict__ Ws, const float* __restrict__ Wr,
    const float* __restrict__ Wqr, const float* __restrict__ Wh,
    ushort_t* __restrict__ wsp, int* __restrict__ deg8)
{
    int tid = blockIdx.x * 256 + threadIdx.x;
    if (tid < NSHARD * N_NODE) deg8[tid] = 0;
    if (tid < 4 * 4096) {
        int w = tid >> 12, e = tid & 4095;
        const float* src = (w == 0) ? Ws : (w == 1) ? Wr : (w == 2) ? Wqr : Wh;
        float f = src[e];
        unsigned u = __float_as_uint(f);
        unsigned r = u + 0x7FFF + ((u >> 16) & 1);
        unsigned short h = (unsigned short)(r >> 16);
        float hf = __uint_as_float(((unsigned)h) << 16);
        float l  = f - hf;
        unsigned u2 = __float_as_uint(l);
        unsigned r2 = u2 + 0x7FFF + ((u2 >> 16) & 1);
        wsp[w * 8192 + e]        = h;
        wsp[w * 8192 + 4096 + e] = (unsigned short)(r2 >> 16);
    }
}

// ---------------------------------------------------------------------------
// gemm64p body (fp32 A, PRE-SPLIT bf16 W). Swapped operands -> packed stores.
// out_mode: 0 fp32 | 1 fp32+relu | 2 bf16 | 3 bf16 + bf16(X) copy to Y2.
// ---------------------------------------------------------------------------
__device__ void gemm64p_body(
    const float* __restrict__ X,
    const int*   __restrict__ idx,
    const ushort_t* __restrict__ Whi,   // [64][64] bf16
    const ushort_t* __restrict__ Wlo,   // [64][64] bf16
    const float* __restrict__ bias,
    void* __restrict__ Yv,
    ushort_t* __restrict__ Y2,
    int R, int out_mode, int blk)
{
    int wave = threadIdx.x >> 6;
    int lane = threadIdx.x & 63;
    int m    = lane & 15;
    int quad = lane >> 4;
    int r0   = blk * 64 + wave * 16;

    int r = r0 + m;
    int src = (r < R) ? (idx ? idx[r] : r) : 0;
    const float* xrow = X + (size_t)src * DIM + quad * 8;

    float4 a0[2], a1[2];
    #pragma unroll
    for (int c = 0; c < 2; ++c) {
        a0[c] = *(const float4*)(xrow + 32 * c);
        a1[c] = *(const float4*)(xrow + 32 * c + 4);
    }
    short8 ah[2], al[2];
    #pragma unroll
    for (int c = 0; c < 2; ++c) split8(a0[c], a1[c], ah[c], al[c]);

    if (out_mode == 3 && r < R) {
        #pragma unroll
        for (int c = 0; c < 2; ++c)
            *(short8*)(Y2 + (size_t)r * DIM + 32 * c + quad * 8) = ah[c];
    }

    floatx4 acc[4] = {{0,0,0,0},{0,0,0,0},{0,0,0,0},{0,0,0,0}};
    #pragma unroll
    for (int g = 0; g < 4; ++g) {
        const ushort_t* whrow = Whi + (size_t)(g * 16 + m) * DIM + quad * 8;
        const ushort_t* wlrow = Wlo + (size_t)(g * 16 + m) * DIM + quad * 8;
        #pragma unroll
        for (int c = 0; c < 2; ++c) {
            short8 bh = *(const short8*)(whrow + 32 * c);
            short8 bl = *(const short8*)(wlrow + 32 * c);
            acc[g] = __builtin_amdgcn_mfma_f32_16x16x32_bf16(bh, ah[c], acc[g], 0, 0, 0);
            acc[g] = __builtin_amdgcn_mfma_f32_16x16x32_bf16(bl, ah[c], acc[g], 0, 0, 0);
            acc[g] = __builtin_amdgcn_mfma_f32_16x16x32_bf16(bh, al[c], acc[g], 0, 0, 0);
        }
    }

    if (r < R) {
        #pragma unroll
        for (int g = 0; g < 4; ++g) {
            float4 bv = make_float4(0.f, 0.f, 0.f, 0.f);
            if (bias) bv = *(const float4*)(bias + g * 16 + quad * 4);
            float v0 = acc[g][0] + bv.x;
            float v1 = acc[g][1] + bv.y;
            float v2 = acc[g][2] + bv.z;
            float v3 = acc[g][3] + bv.w;
            if (out_mode == 1) {
                v0 = fmaxf(v0, 0.f); v1 = fmaxf(v1, 0.f);
                v2 = fmaxf(v2, 0.f); v3 = fmaxf(v3, 0.f);
            }
            if (out_mode >= 2) {
                uint2 o;
                o.x = (unsigned)f2bf_rne(v0) | ((unsigned)f2bf_rne(v1) << 16);
                o.y = (unsigned)f2bf_rne(v2) | ((unsigned)f2bf_rne(v3) << 16);
                *(uint2*)((ushort_t*)Yv + (size_t)r * DIM + g * 16 + quad * 4) = o;
            } else {
                *(float4*)((float*)Yv + (size_t)r * DIM + g * 16 + quad * 4) =
                    make_float4(v0, v1, v2, v3);
            }
        }
    }
}

// ---------------------------------------------------------------------------
// Final gemm, bf16 A, pre-split W: Y[r] = relu( A[r] @ W^T ), fp32 out.
// ---------------------------------------------------------------------------
__global__ __launch_bounds__(256) void gemm64p_bf16A_kernel(
    const ushort_t* __restrict__ A,
    const ushort_t* __restrict__ Whi,
    const ushort_t* __restrict__ Wlo,
    float* __restrict__ Y, int R)
{
    int wave = threadIdx.x >> 6;
    int lane = threadIdx.x & 63;
    int m    = lane & 15;
    int quad = lane >> 4;
    int r0   = blockIdx.x * 64 + wave * 16;

    int r = r0 + m;
    int src = (r < R) ? r : 0;
    short8 a8[2];
    #pragma unroll
    for (int c = 0; c < 2; ++c)
        a8[c] = *(const short8*)(A + (size_t)src * DIM + 32 * c + quad * 8);

    floatx4 acc[4] = {{0,0,0,0},{0,0,0,0},{0,0,0,0},{0,0,0,0}};
    #pragma unroll
    for (int g = 0; g < 4; ++g) {
        const ushort_t* whrow = Whi + (size_t)(g * 16 + m) * DIM + quad * 8;
        const ushort_t* wlrow = Wlo + (size_t)(g * 16 + m) * DIM + quad * 8;
        #pragma unroll
        for (int c = 0; c < 2; ++c) {
            short8 bh = *(const short8*)(whrow + 32 * c);
            short8 bl = *(const short8*)(wlrow + 32 * c);
            acc[g] = __builtin_amdgcn_mfma_f32_16x16x32_bf16(bh, a8[c], acc[g], 0, 0, 0);
            acc[g] = __builtin_amdgcn_mfma_f32_16x16x32_bf16(bl, a8[c], acc[g], 0, 0, 0);
        }
    }

    if (r < R) {
        #pragma unroll
        for (int g = 0; g < 4; ++g) {
            *(float4*)(Y + (size_t)r * DIM + g * 16 + quad * 4) =
                make_float4(fmaxf(acc[g][0], 0.f), fmaxf(acc[g][1], 0.f),
                            fmaxf(acc[g][2], 0.f), fmaxf(acc[g][3], 0.f));
        }
    }
}

// ---------------------------------------------------------------------------
// OLD fp32-W gemm body (fallback path only).
// ---------------------------------------------------------------------------
__device__ void gemm64_body(
    const float* __restrict__ X,
    const int*   __restrict__ idx,
    const float* __restrict__ W,
    const float* __restrict__ bias,
    void* __restrict__ Yv,
    ushort_t* __restrict__ Y2,
    int R, int out_mode, int blk)
{
    int wave = threadIdx.x >> 6;
    int lane = threadIdx.x & 63;
    int m    = lane & 15;
    int quad = lane >> 4;
    int r0   = blk * 64 + wave * 16;

    int r = r0 + m;
    int src = (r < R) ? (idx ? idx[r] : r) : 0;
    const float* xrow = X + (size_t)src * DIM + quad * 8;

    float4 a0[2], a1[2];
    #pragma unroll
    for (int c = 0; c < 2; ++c) {
        a0[c] = *(const float4*)(xrow + 32 * c);
        a1[c] = *(const float4*)(xrow + 32 * c + 4);
    }
    short8 ah[2], al[2];
    #pragma unroll
    for (int c = 0; c < 2; ++c) split8(a0[c], a1[c], ah[c], al[c]);

    if (out_mode == 3 && r < R) {
        #pragma unroll
        for (int c = 0; c < 2; ++c)
            *(short8*)(Y2 + (size_t)r * DIM + 32 * c + quad * 8) = ah[c];
    }

    floatx4 acc[4] = {{0,0,0,0},{0,0,0,0},{0,0,0,0},{0,0,0,0}};
    #pragma unroll
    for (int g = 0; g < 4; ++g) {
        const float* wrow = W + (size_t)(g * 16 + m) * DIM + quad * 8;
        #pragma unroll
        for (int c = 0; c < 2; ++c) {
            float4 b0 = *(const float4*)(wrow + 32 * c);
            float4 b1 = *(const float4*)(wrow + 32 * c + 4);
            short8 bh, bl;
            split8(b0, b1, bh, bl);
            acc[g] = __builtin_amdgcn_mfma_f32_16x16x32_bf16(ah[c], bh, acc[g], 0, 0, 0);
            acc[g] = __builtin_amdgcn_mfma_f32_16x16x32_bf16(ah[c], bl, acc[g], 0, 0, 0);
            acc[g] = __builtin_amdgcn_mfma_f32_16x16x32_bf16(al[c], bh, acc[g], 0, 0, 0);
        }
    }

    #pragma unroll
    for (int g = 0; g < 4; ++g) {
        float bv = bias ? bias[g * 16 + m] : 0.0f;
        #pragma unroll
        for (int reg = 0; reg < 4; ++reg) {
            int rr = r0 + quad * 4 + reg;
            if (rr < R) {
                float v = acc[g][reg] + bv;
                if (out_mode == 1) v = fmaxf(v, 0.0f);
                if (out_mode >= 2)
                    ((ushort_t*)Yv)[(size_t)rr * DIM + g * 16 + m] = f2bf_rne(v);
                else
                    ((float*)Yv)[(size_t)rr * DIM + g * 16 + m] = v;
            }
        }
    }
}

__global__ __launch_bounds__(256) void gemm64_kernel(
    const float* __restrict__ X, const int* __restrict__ idx,
    const float* __restrict__ W, const float* __restrict__ bias,
    void* __restrict__ Yv, ushort_t* __restrict__ Y2, int R, int out_mode)
{
    gemm64_body(X, idx, W, bias, Yv, Y2, R, out_mode, blockIdx.x);
}

// ---------------------------------------------------------------------------
// deg: SPLIT OUT of prep for per-phase rocprof visibility. 489 blocks x 2048
// edges, 8 edges/thread, device-scope atomics on 8 edge-chunk shards
// (round-1 structure: known 57us fused; measures alone now).
// ---------------------------------------------------------------------------
#define GD8 ((N_EDGE + EPB - 1) / EPB)     // 489

__global__ __launch_bounds__(256) void deg_kernel(
    const int* __restrict__ edges,
    int* __restrict__ deg8,        // [8][N_NODE], pre-zeroed by init
    int* __restrict__ rank,
    int2* __restrict__ epack)
{
    int base = blockIdx.x * EPB + threadIdx.x;
    #pragma unroll
    for (int k = 0; k < 8; ++k) {
        int e = base + k * 256;
        if (e < N_EDGE) {
            int2 ab = *(const int2*)(edges + (size_t)e * 6);      // (r_idx,0)
            int2 cd = *(const int2*)(edges + (size_t)e * 6 + 2);  // (rel,0)
            int2 ef = *(const int2*)(edges + (size_t)e * 6 + 4);  // (sub,obj)
            epack[e] = make_int2(ef.x | (cd.x << 17), ef.y | (ab.x << 17));
            int s = (e >> 11) & (NSHARD - 1);
            rank[e] = atomicAdd(&deg8[s * N_NODE + ef.y], 1);
        }
    }
}

// ---------------------------------------------------------------------------
// gemmprep: the three input gemms (rel, qr, hsWs), SPLIT OUT of prep.
// ---------------------------------------------------------------------------
#define G1 ((N_NODE + 63) / 64)            // 1563
#define G2 ((NVOCAB + 63) / 64)            // 7
#define G3 (NB / 64)                       // 4
#define GSMALL (G2 + G3)                   // 11
#define GEMMPREP_GRID (GSMALL + G1)

__global__ __launch_bounds__(256) void gemmprep_kernel(
    const float* __restrict__ hidden,
    const float* __restrict__ rela,
    const int*   __restrict__ q_rel,
    const ushort_t* __restrict__ wsp,   // pre-split weights
    const float* __restrict__ Wqr_b,
    ushort_t* __restrict__ hsWs,
    ushort_t* __restrict__ hidb,
    ushort_t* __restrict__ rel_preb,
    ushort_t* __restrict__ relab,
    ushort_t* __restrict__ qr_preb)
{
    int b = blockIdx.x;
    if (b < G2) {
        gemm64p_body(rela, nullptr, wsp + 1 * 8192, wsp + 1 * 8192 + 4096,
                     nullptr, rel_preb, relab, NVOCAB, 3, b);
    } else if (b < GSMALL) {
        gemm64p_body(rela, q_rel, wsp + 2 * 8192, wsp + 2 * 8192 + 4096,
                     Wqr_b, qr_preb, nullptr, NB, 2, b - G2);
    } else {
        gemm64p_body(hidden, nullptr, wsp, wsp + 4096,
                     nullptr, hsWs, hidb, N_NODE, 3, b - GSMALL);
    }
}

// ---------------------------------------------------------------------------
// CSR scan pipeline over sharded counters.
// ---------------------------------------------------------------------------
__global__ __launch_bounds__(SCAN_B) void scan1_kernel(const int* __restrict__ deg8,
                                                       int* __restrict__ partial)
{
    __shared__ int s[SCAN_B];
    int g = blockIdx.x * SCAN_B + threadIdx.x;
    int tot = 0;
    if (g < N_NODE)
        #pragma unroll
        for (int k = 0; k < NSHARD; ++k) tot += deg8[k * N_NODE + g];
    s[threadIdx.x] = tot;
    __syncthreads();
    for (int off = SCAN_B / 2; off; off >>= 1) {
        if (threadIdx.x < off) s[threadIdx.x] += s[threadIdx.x + off];
        __syncthreads();
    }
    if (threadIdx.x == 0) partial[blockIdx.x] = s[0];
}

__global__ __launch_bounds__(128) void scan2_kernel(int* __restrict__ partial, int n)
{
    __shared__ int s[128];
    int t = threadIdx.x;
    int v = (t < n) ? partial[t] : 0;
    s[t] = v;
    __syncthreads();
    for (int off = 1; off < 128; off <<= 1) {
        int add = (t >= off) ? s[t - off] : 0;
        __syncthreads();
        s[t] += add;
        __syncthreads();
    }
    if (t < n) partial[t] = s[t] - v;   // exclusive
}

// scan3: offs[g+1] = global inclusive; rewrites deg8 in place into per-shard
// slot bases: deg8[s][g] <- offs[g] + sum_{s'<s} deg_s'(g).
__global__ __launch_bounds__(SCAN_B) void scan3_kernel(int* __restrict__ deg8,
                                                       const int* __restrict__ partial,
                                                       int* __restrict__ offs)
{
    __shared__ int s[SCAN_B];
    int g = blockIdx.x * SCAN_B + threadIdx.x;
    int d[NSHARD];
    int tot = 0;
    if (g < N_NODE) {
        #pragma unroll
        for (int k = 0; k < NSHARD; ++k) { d[k] = deg8[k * N_NODE + g]; tot += d[k]; }
    }
    s[threadIdx.x] = tot;
    __syncthreads();
    for (int off = 1; off < SCAN_B; off <<= 1) {
        int add = ((int)threadIdx.x >= off) ? s[threadIdx.x - off] : 0;
        __syncthreads();
        s[threadIdx.x] += add;
        __syncthreads();
    }
    if (g < N_NODE) {
        int incl = partial[blockIdx.x] + s[threadIdx.x];
        offs[g + 1] = incl;
        if (g == 0) offs[0] = 0;
        int run = incl - tot;                     // = offs[g]
        #pragma unroll
        for (int k = 0; k < NSHARD; ++k) { deg8[k * N_NODE + g] = run; run += d[k]; }
    }
}

// ---------------------------------------------------------------------------
// alpha + scatter: reads only epack (8B coalesced) + rank + bf16 tables.
// Quarter-wave, 4 edges/quarter, 64 edges/block. slot = base8[shard][obj]+rank.
// ---------------------------------------------------------------------------
__global__ __launch_bounds__(256) void alpha_scatter_kernel(
    const int2*     __restrict__ epack,
    const int*      __restrict__ rank,
    const int*      __restrict__ base8,     // deg8 transformed by scan3
    const ushort_t* __restrict__ hsWs,
    const ushort_t* __restrict__ rel_preb,
    const ushort_t* __restrict__ qr_preb,
    const float*    __restrict__ wattn,
    int2*           __restrict__ csr2)
{
    int tid = blockIdx.x * 256 + threadIdx.x;
    if (tid < 4) csr2[N_EDGE + tid] = make_int2(0, 0);

    int wave = threadIdx.x >> 6;
    int lane = threadIdx.x & 63;
    int q    = lane >> 4;
    int l    = lane & 15;
    int f0   = l * 4;
    int e0   = (blockIdx.x * 4 + wave) * 16 + q * 4;

    float4 wa = *(const float4*)(wattn + f0);

    int   sub[4], rl[4], ob[4];
    float t[4];
    #pragma unroll
    for (int j = 0; j < 4; ++j) {
        int e = e0 + j;
        int2 ep = epack[e];
        sub[j] = ep.x & 0x1FFFF;
        rl[j]  = (int)((unsigned)ep.x >> 17);
        ob[j]  = ep.y & 0x1FFFF;
        int ri = (int)((unsigned)ep.y >> 17);

        uint2 uh = *(const uint2*)(hsWs     + (size_t)sub[j] * DIM + f0);
        uint2 ur = *(const uint2*)(rel_preb + (size_t)rl[j]  * DIM + f0);
        uint2 uq = *(const uint2*)(qr_preb  + (size_t)ri     * DIM + f0);

        float tt =  fmaxf(bflo(uh.x) + bflo(ur.x) + bflo(uq.x), 0.f) * wa.x;
        tt = fmaf(fmaxf(bfhi(uh.x) + bfhi(ur.x) + bfhi(uq.x), 0.f), wa.y, tt);
        tt = fmaf(fmaxf(bflo(uh.y) + bflo(ur.y) + bflo(uq.y), 0.f), wa.z, tt);
        tt = fmaf(fmaxf(bfhi(uh.y) + bfhi(ur.y) + bfhi(uq.y), 0.f), wa.w, tt);
        t[j] = tt;
    }
    #pragma unroll
    for (int j = 0; j < 4; ++j) {
        t[j] += __shfl_xor(t[j], 1);
        t[j] += __shfl_xor(t[j], 2);
        t[j] += __shfl_xor(t[j], 4);
        t[j] += __shfl_xor(t[j], 8);
    }

    if (l < 4) {
        int j = l;
        int e = e0 + j;
        int sh = (e0 >> 11) & (NSHARD - 1);      // all 4 edges share a 2048-chunk
        float alpha = 1.0f / (1.0f + __expf(-t[j]));
        int slot = base8[sh * N_NODE + ob[j]] + rank[e];
        csr2[slot] = make_int2(sub[j],
            (int)(((unsigned)rl[j] << 16) | f2h(alpha)));
    }
}

// ---------------------------------------------------------------------------
// Aggregation: persistent waves, 8 edges/iter, bf16 output.
// ---------------------------------------------------------------------------
__global__ __launch_bounds__(256) void agg_kernel(
    const int2*     __restrict__ csr2,
    const int*      __restrict__ offs,
    const ushort_t* __restrict__ hB,
    const ushort_t* __restrict__ relab,
    ushort_t* __restrict__ aggb)         // bf16 [N_NODE][64]
{
    int lane = threadIdx.x & 63;
    int q    = lane >> 4;
    int l    = lane & 15;
    int f0   = l * 4;
    int wv = __builtin_amdgcn_readfirstlane((blockIdx.x * blockDim.x + threadIdx.x) >> 6);

    int i   = offs[wv];
    int end = offs[wv + 1];
    for (int n = wv; n < N_NODE; n += AGG_WAVES) {
        int nn = n + AGG_WAVES;
        int ni = 0, ne = 0;
        if (nn < N_NODE) { ni = offs[nn]; ne = offs[nn + 1]; }

        float4 acc = make_float4(0.f, 0.f, 0.f, 0.f);
        int2 e0 = csr2[min(i + q,     N_EDGE + 3)];
        int2 e1 = csr2[min(i + 4 + q, N_EDGE + 3)];
        while (i < end) {
            int2 f0e = csr2[min(i + 8 + q,  N_EDGE + 3)];
            int2 f1e = csr2[min(i + 12 + q, N_EDGE + 3)];
            float v0 = (i + q < end)     ? 1.0f : 0.0f;
            float v1 = (i + 4 + q < end) ? 1.0f : 0.0f;

            unsigned ey0 = (unsigned)e0.y, ey1 = (unsigned)e1.y;
            float al0 = v0 * h2f(ey0 & 0xFFFFu);
            float al1 = v1 * h2f(ey1 & 0xFFFFu);

            uint2 uh0 = *(const uint2*)(hB    + (size_t)e0.x        * DIM + f0);
            uint2 ur0 = *(const uint2*)(relab + (size_t)(ey0 >> 16) * DIM + f0);
            uint2 uh1 = *(const uint2*)(hB    + (size_t)e1.x        * DIM + f0);
            uint2 ur1 = *(const uint2*)(relab + (size_t)(ey1 >> 16) * DIM + f0);

            acc.x = fmaf(al0, bflo(uh0.x) + bflo(ur0.x), acc.x);
            acc.y = fmaf(al0, bfhi(uh0.x) + bfhi(ur0.x), acc.y);
            acc.z = fmaf(al0, bflo(uh0.y) + bflo(ur0.y), acc.z);
            acc.w = fmaf(al0, bfhi(uh0.y) + bfhi(ur0.y), acc.w);
            acc.x = fmaf(al1, bflo(uh1.x) + bflo(ur1.x), acc.x);
            acc.y = fmaf(al1, bfhi(uh1.x) + bfhi(ur1.x), acc.y);
            acc.z = fmaf(al1, bflo(uh1.y) + bflo(ur1.y), acc.z);
            acc.w = fmaf(al1, bfhi(uh1.y) + bfhi(ur1.y), acc.w);

            e0 = f0e; e1 = f1e;
            i += 8;
        }

        acc.x += __shfl_xor(acc.x, 16); acc.x += __shfl_xor(acc.x, 32);
        acc.y += __shfl_xor(acc.y, 16); acc.y += __shfl_xor(acc.y, 32);
        acc.z += __shfl_xor(acc.z, 16); acc.z += __shfl_xor(acc.z, 32);
        acc.w += __shfl_xor(acc.w, 16); acc.w += __shfl_xor(acc.w, 32);
        if (q == 0) {
            uint2 o;
            o.x = (unsigned)f2bf_rne(acc.x) | ((unsigned)f2bf_rne(acc.y) << 16);
            o.y = (unsigned)f2bf_rne(acc.z) | ((unsigned)f2bf_rne(acc.w) << 16);
            *(uint2*)(aggb + (size_t)n * DIM + f0) = o;
        }

        i = ni; end = ne;
    }
}

// ---------------------------------------------------------------------------
// Fallback (ws too small): wave-per-edge atomic kernel, bf16 tables.
// ---------------------------------------------------------------------------
__global__ __launch_bounds__(256) void edge_kernel(
    const int*      __restrict__ edges,
    const ushort_t* __restrict__ hB,
    const ushort_t* __restrict__ relab,
    const ushort_t* __restrict__ hsWs,
    const ushort_t* __restrict__ rel_preb,
    const ushort_t* __restrict__ qr_preb,
    const float*    __restrict__ wattn,
    float* __restrict__ out)
{
    int e = (blockIdx.x * blockDim.x + threadIdx.x) >> 6;
    if (e >= N_EDGE) return;
    int lane = threadIdx.x & 63;
    int r_i = edges[e * 6 + 0];
    int rl  = edges[e * 6 + 2];
    int sb  = edges[e * 6 + 4];
    int ob  = edges[e * 6 + 5];
    float hs = __uint_as_float(((unsigned)hB[(size_t)sb * DIM + lane]) << 16);
    float hr = __uint_as_float(((unsigned)relab[(size_t)rl * DIM + lane]) << 16);
    float p1 = __uint_as_float(((unsigned)hsWs[(size_t)sb * DIM + lane]) << 16);
    float p2 = __uint_as_float(((unsigned)rel_preb[(size_t)rl * DIM + lane]) << 16);
    float p3 = __uint_as_float(((unsigned)qr_preb[(size_t)r_i * DIM + lane]) << 16);
    float t = wattn[lane] * fmaxf(p1 + p2 + p3, 0.0f);
    #pragma unroll
    for (int off = 32; off; off >>= 1) t += __shfl_xor(t, off);
    float alpha = 1.0f / (1.0f + __expf(-t));
    atomicAdd(&out[(size_t)ob * DIM + lane], (hs + hr) * alpha);
}

extern "C" void kernel_launch(void* const* d_in, const int* in_sizes, int n_in,
                              void* d_out, int out_size, void* d_ws, size_t ws_size,
                              hipStream_t stream)
{
    const float* hidden = (const float*)d_in[0];
    const int*   q_rel  = (const int*)  d_in[1];
    const int*   edges  = (const int*)  d_in[2];
    const float* rela   = (const float*)d_in[3];
    const float* Ws     = (const float*)d_in[4];
    const float* Wr     = (const float*)d_in[5];
    const float* Wqr    = (const float*)d_in[6];
    const float* Wqr_b  = (const float*)d_in[7];
    const float* Wattn  = (const float*)d_in[8];
    const float* Wh     = (const float*)d_in[9];
    float* out = (float*)d_out;

    // ---- workspace layout ----
    ushort_t* qr_preb  = (ushort_t*)d_ws;                 // 256*64 bf16
    ushort_t* rel_preb = qr_preb + NB * DIM;              // 401*64 bf16
    ushort_t* relab    = rel_preb + NVOCAB * DIM;         // 401*64 bf16
    ushort_t* hsWs     = relab + NVOCAB * DIM;            // 100000*64 bf16
    ushort_t* hidb     = hsWs + (size_t)N_NODE * DIM;     // 100000*64 bf16
    int2* epack  = (int2*)(((uintptr_t)(hidb + (size_t)N_NODE * DIM) + 15) & ~(uintptr_t)15);
    int*  rank   = (int*)(epack + N_EDGE);                // N_EDGE
    int*  deg8   = rank + N_EDGE;                         // 8*N_NODE
    int*  offs   = deg8 + NSHARD * N_NODE;                // N_NODE+1
    int*  partial= offs + (N_NODE + 1);                   // 128
    int2* csr2   = (int2*)(((uintptr_t)(partial + 128) + 15) & ~(uintptr_t)15);
    ushort_t* wsp = (ushort_t*)(csr2 + N_EDGE + 4);       // 4*2*4096 bf16 (64KB)
    size_t csr_need = ((char*)(wsp + 4 * 8192)) - (char*)d_ws;
    bool use_csr = ws_size >= csr_need;
    // aggb aliases the dead epack/rank/deg8 region (15.2MB >= 12.8MB needed);
    // epack/rank/deg8 are dead after alpha_scatter; csr2/offs/wsp stay intact.
    ushort_t* aggb = (ushort_t*)epack;

    if (use_csr) {
        init_kernel<<<INIT_GRID, 256, 0, stream>>>(Ws, Wr, Wqr, Wh, wsp, deg8);
        deg_kernel<<<GD8, 256, 0, stream>>>(edges, deg8, rank, epack);
        gemmprep_kernel<<<GEMMPREP_GRID, 256, 0, stream>>>(
            hidden, rela, q_rel, wsp, Wqr_b,
            hsWs, hidb, rel_preb, relab, qr_preb);
        scan1_kernel<<<NCHUNK, SCAN_B, 0, stream>>>(deg8, partial);
        scan2_kernel<<<1, 128, 0, stream>>>(partial, NCHUNK);
        scan3_kernel<<<NCHUNK, SCAN_B, 0, stream>>>(deg8, partial, offs);
        alpha_scatter_kernel<<<N_EDGE / 64, 256, 0, stream>>>(
            epack, rank, deg8, hsWs, rel_preb, qr_preb, Wattn, csr2);
        agg_kernel<<<AGG_WAVES / 4, 256, 0, stream>>>(csr2, offs, hidb, relab, aggb);
        gemm64p_bf16A_kernel<<<(N_NODE + 63) / 64, 256, 0, stream>>>(
            aggb, wsp + 3 * 8192, wsp + 3 * 8192 + 4096, out, N_NODE);
    } else {
        gemm64_kernel<<<(NVOCAB + 63) / 64, 256, 0, stream>>>(
            rela, nullptr, Wr, nullptr, rel_preb, relab, NVOCAB, 3);
        gemm64_kernel<<<(NB + 63) / 64, 256, 0, stream>>>(
            rela, q_rel, Wqr, Wqr_b, qr_preb, nullptr, NB, 2);
        gemm64_kernel<<<(N_NODE + 63) / 64, 256, 0, stream>>>(
            hidden, nullptr, Ws, nullptr, hsWs, hidb, N_NODE, 3);
        hipMemsetAsync(d_out, 0, (size_t)N_NODE * DIM * sizeof(float), stream);
        edge_kernel<<<(N_EDGE + 3) / 4, 256, 0, stream>>>(
            edges, hidb, relab, hsWs, rel_preb, qr_preb, Wattn, out);
        gemm64_kernel<<<(N_NODE + 63) / 64, 256, 0, stream>>>(
            out, nullptr, Wh, nullptr, out, nullptr, N_NODE, 1);
    }
}

// Round 4
// 259.196 us; speedup vs baseline: 1.4013x; 1.0446x over previous
//
#include <hip/hip_runtime.h>
#include <math.h>
#include <stdint.h>

#define N_NODE 100000
#define N_EDGE 1000000
#define DIM    64
#define NB     256
#define NVOCAB 401
#define SCAN_B 1024
#define NCHUNK ((N_NODE + SCAN_B - 1) / SCAN_B)
#define AGG_WAVES 8192
#define NSHARD 8
#define EPB 2048            // edges per deg block (256 thr x 8)

typedef short short8  __attribute__((ext_vector_type(8)));
typedef float floatx4 __attribute__((ext_vector_type(4)));
typedef unsigned short ushort_t;

__device__ inline unsigned short f2bf_rne(float f)
{
    unsigned u = __float_as_uint(f);
    unsigned r = u + 0x7FFF + ((u >> 16) & 1);
    return (unsigned short)(r >> 16);
}
__device__ inline float bflo(unsigned u) { return __uint_as_float(u << 16); }
__device__ inline float bfhi(unsigned u) { return __uint_as_float(u & 0xFFFF0000u); }
__device__ inline unsigned short f2h(float f)
{
    _Float16 h = (_Float16)f;
    unsigned short s; __builtin_memcpy(&s, &h, 2); return s;
}
__device__ inline float h2f(unsigned b)
{
    unsigned short s = (unsigned short)b;
    _Float16 h; __builtin_memcpy(&h, &s, 2); return (float)h;
}

__device__ inline void split8(float4 v0, float4 v1, short8& hi, short8& lo)
{
    float f[8] = {v0.x, v0.y, v0.z, v0.w, v1.x, v1.y, v1.z, v1.w};
    #pragma unroll
    for (int j = 0; j < 8; ++j) {
        unsigned u = __float_as_uint(f[j]);
        unsigned r = u + 0x7FFF + ((u >> 16) & 1);
        unsigned short h = (unsigned short)(r >> 16);
        float hf = __uint_as_float(((unsigned)h) << 16);
        float l  = f[j] - hf;
        unsigned u2 = __float_as_uint(l);
        unsigned r2 = u2 + 0x7FFF + ((u2 >> 16) & 1);
        hi[j] = (short)h;
        lo[j] = (short)(r2 >> 16);
    }
}

// ---------------------------------------------------------------------------
// init: zero deg8 AND pre-split the 4 weight matrices into bf16 hi/lo tables.
// wsp layout: [w][2][4096] bf16, w: 0=Ws 1=Wr 2=Wqr 3=Wh.
// ---------------------------------------------------------------------------
#define INIT_GRID ((NSHARD * N_NODE + 255) / 256)

__global__ __launch_bounds__(256) void init_kernel(
    const float* __restrict__ Ws, const float* __restrict__ Wr,
    const float* __restrict__ Wqr, const float* __restrict__ Wh,
    ushort_t* __restrict__ wsp, int* __restrict__ deg8)
{
    int tid = blockIdx.x * 256 + threadIdx.x;
    if (tid < NSHARD * N_NODE) deg8[tid] = 0;
    if (tid < 4 * 4096) {
        int w = tid >> 12, e = tid & 4095;
        const float* src = (w == 0) ? Ws : (w == 1) ? Wr : (w == 2) ? Wqr : Wh;
        float f = src[e];
        unsigned u = __float_as_uint(f);
        unsigned r = u + 0x7FFF + ((u >> 16) & 1);
        unsigned short h = (unsigned short)(r >> 16);
        float hf = __uint_as_float(((unsigned)h) << 16);
        float l  = f - hf;
        unsigned u2 = __float_as_uint(l);
        unsigned r2 = u2 + 0x7FFF + ((u2 >> 16) & 1);
        wsp[w * 8192 + e]        = h;
        wsp[w * 8192 + 4096 + e] = (unsigned short)(r2 >> 16);
    }
}

// ---------------------------------------------------------------------------
// gemm64p body (fp32 A, PRE-SPLIT bf16 W). Swapped operands -> packed stores.
// out_mode: 0 fp32 | 1 fp32+relu | 2 bf16 | 3 bf16 + bf16(X) copy to Y2.
// ---------------------------------------------------------------------------
__device__ void gemm64p_body(
    const float* __restrict__ X,
    const int*   __restrict__ idx,
    const ushort_t* __restrict__ Whi,   // [64][64] bf16
    const ushort_t* __restrict__ Wlo,   // [64][64] bf16
    const float* __restrict__ bias,
    void* __restrict__ Yv,
    ushort_t* __restrict__ Y2,
    int R, int out_mode, int blk)
{
    int wave = threadIdx.x >> 6;
    int lane = threadIdx.x & 63;
    int m    = lane & 15;
    int quad = lane >> 4;
    int r0   = blk * 64 + wave * 16;

    int r = r0 + m;
    int src = (r < R) ? (idx ? idx[r] : r) : 0;
    const float* xrow = X + (size_t)src * DIM + quad * 8;

    float4 a0[2], a1[2];
    #pragma unroll
    for (int c = 0; c < 2; ++c) {
        a0[c] = *(const float4*)(xrow + 32 * c);
        a1[c] = *(const float4*)(xrow + 32 * c + 4);
    }
    short8 ah[2], al[2];
    #pragma unroll
    for (int c = 0; c < 2; ++c) split8(a0[c], a1[c], ah[c], al[c]);

    if (out_mode == 3 && r < R) {
        #pragma unroll
        for (int c = 0; c < 2; ++c)
            *(short8*)(Y2 + (size_t)r * DIM + 32 * c + quad * 8) = ah[c];
    }

    floatx4 acc[4] = {{0,0,0,0},{0,0,0,0},{0,0,0,0},{0,0,0,0}};
    #pragma unroll
    for (int g = 0; g < 4; ++g) {
        const ushort_t* whrow = Whi + (size_t)(g * 16 + m) * DIM + quad * 8;
        const ushort_t* wlrow = Wlo + (size_t)(g * 16 + m) * DIM + quad * 8;
        #pragma unroll
        for (int c = 0; c < 2; ++c) {
            short8 bh = *(const short8*)(whrow + 32 * c);
            short8 bl = *(const short8*)(wlrow + 32 * c);
            acc[g] = __builtin_amdgcn_mfma_f32_16x16x32_bf16(bh, ah[c], acc[g], 0, 0, 0);
            acc[g] = __builtin_amdgcn_mfma_f32_16x16x32_bf16(bl, ah[c], acc[g], 0, 0, 0);
            acc[g] = __builtin_amdgcn_mfma_f32_16x16x32_bf16(bh, al[c], acc[g], 0, 0, 0);
        }
    }

    if (r < R) {
        #pragma unroll
        for (int g = 0; g < 4; ++g) {
            float4 bv = make_float4(0.f, 0.f, 0.f, 0.f);
            if (bias) bv = *(const float4*)(bias + g * 16 + quad * 4);
            float v0 = acc[g][0] + bv.x;
            float v1 = acc[g][1] + bv.y;
            float v2 = acc[g][2] + bv.z;
            float v3 = acc[g][3] + bv.w;
            if (out_mode == 1) {
                v0 = fmaxf(v0, 0.f); v1 = fmaxf(v1, 0.f);
                v2 = fmaxf(v2, 0.f); v3 = fmaxf(v3, 0.f);
            }
            if (out_mode >= 2) {
                uint2 o;
                o.x = (unsigned)f2bf_rne(v0) | ((unsigned)f2bf_rne(v1) << 16);
                o.y = (unsigned)f2bf_rne(v2) | ((unsigned)f2bf_rne(v3) << 16);
                *(uint2*)((ushort_t*)Yv + (size_t)r * DIM + g * 16 + quad * 4) = o;
            } else {
                *(float4*)((float*)Yv + (size_t)r * DIM + g * 16 + quad * 4) =
                    make_float4(v0, v1, v2, v3);
            }
        }
    }
}

// ---------------------------------------------------------------------------
// Final gemm, bf16 A, pre-split W: Y[r] = relu( A[r] @ W^T ), fp32 out.
// ---------------------------------------------------------------------------
__global__ __launch_bounds__(256) void gemm64p_bf16A_kernel(
    const ushort_t* __restrict__ A,
    const ushort_t* __restrict__ Whi,
    const ushort_t* __restrict__ Wlo,
    float* __restrict__ Y, int R)
{
    int wave = threadIdx.x >> 6;
    int lane = threadIdx.x & 63;
    int m    = lane & 15;
    int quad = lane >> 4;
    int r0   = blockIdx.x * 64 + wave * 16;

    int r = r0 + m;
    int src = (r < R) ? r : 0;
    short8 a8[2];
    #pragma unroll
    for (int c = 0; c < 2; ++c)
        a8[c] = *(const short8*)(A + (size_t)src * DIM + 32 * c + quad * 8);

    floatx4 acc[4] = {{0,0,0,0},{0,0,0,0},{0,0,0,0},{0,0,0,0}};
    #pragma unroll
    for (int g = 0; g < 4; ++g) {
        const ushort_t* whrow = Whi + (size_t)(g * 16 + m) * DIM + quad * 8;
        const ushort_t* wlrow = Wlo + (size_t)(g * 16 + m) * DIM + quad * 8;
        #pragma unroll
        for (int c = 0; c < 2; ++c) {
            short8 bh = *(const short8*)(whrow + 32 * c);
            short8 bl = *(const short8*)(wlrow + 32 * c);
            acc[g] = __builtin_amdgcn_mfma_f32_16x16x32_bf16(bh, a8[c], acc[g], 0, 0, 0);
            acc[g] = __builtin_amdgcn_mfma_f32_16x16x32_bf16(bl, a8[c], acc[g], 0, 0, 0);
        }
    }

    if (r < R) {
        #pragma unroll
        for (int g = 0; g < 4; ++g) {
            *(float4*)(Y + (size_t)r * DIM + g * 16 + quad * 4) =
                make_float4(fmaxf(acc[g][0], 0.f), fmaxf(acc[g][1], 0.f),
                            fmaxf(acc[g][2], 0.f), fmaxf(acc[g][3], 0.f));
        }
    }
}

// ---------------------------------------------------------------------------
// OLD fp32-W gemm body (fallback path only).
// ---------------------------------------------------------------------------
__device__ void gemm64_body(
    const float* __restrict__ X,
    const int*   __restrict__ idx,
    const float* __restrict__ W,
    const float* __restrict__ bias,
    void* __restrict__ Yv,
    ushort_t* __restrict__ Y2,
    int R, int out_mode, int blk)
{
    int wave = threadIdx.x >> 6;
    int lane = threadIdx.x & 63;
    int m    = lane & 15;
    int quad = lane >> 4;
    int r0   = blk * 64 + wave * 16;

    int r = r0 + m;
    int src = (r < R) ? (idx ? idx[r] : r) : 0;
    const float* xrow = X + (size_t)src * DIM + quad * 8;

    float4 a0[2], a1[2];
    #pragma unroll
    for (int c = 0; c < 2; ++c) {
        a0[c] = *(const float4*)(xrow + 32 * c);
        a1[c] = *(const float4*)(xrow + 32 * c + 4);
    }
    short8 ah[2], al[2];
    #pragma unroll
    for (int c = 0; c < 2; ++c) split8(a0[c], a1[c], ah[c], al[c]);

    if (out_mode == 3 && r < R) {
        #pragma unroll
        for (int c = 0; c < 2; ++c)
            *(short8*)(Y2 + (size_t)r * DIM + 32 * c + quad * 8) = ah[c];
    }

    floatx4 acc[4] = {{0,0,0,0},{0,0,0,0},{0,0,0,0},{0,0,0,0}};
    #pragma unroll
    for (int g = 0; g < 4; ++g) {
        const float* wrow = W + (size_t)(g * 16 + m) * DIM + quad * 8;
        #pragma unroll
        for (int c = 0; c < 2; ++c) {
            float4 b0 = *(const float4*)(wrow + 32 * c);
            float4 b1 = *(const float4*)(wrow + 32 * c + 4);
            short8 bh, bl;
            split8(b0, b1, bh, bl);
            acc[g] = __builtin_amdgcn_mfma_f32_16x16x32_bf16(ah[c], bh, acc[g], 0, 0, 0);
            acc[g] = __builtin_amdgcn_mfma_f32_16x16x32_bf16(ah[c], bl, acc[g], 0, 0, 0);
            acc[g] = __builtin_amdgcn_mfma_f32_16x16x32_bf16(al[c], bh, acc[g], 0, 0, 0);
        }
    }

    #pragma unroll
    for (int g = 0; g < 4; ++g) {
        float bv = bias ? bias[g * 16 + m] : 0.0f;
        #pragma unroll
        for (int reg = 0; reg < 4; ++reg) {
            int rr = r0 + quad * 4 + reg;
            if (rr < R) {
                float v = acc[g][reg] + bv;
                if (out_mode == 1) v = fmaxf(v, 0.0f);
                if (out_mode >= 2)
                    ((ushort_t*)Yv)[(size_t)rr * DIM + g * 16 + m] = f2bf_rne(v);
                else
                    ((float*)Yv)[(size_t)rr * DIM + g * 16 + m] = v;
            }
        }
    }
}

__global__ __launch_bounds__(256) void gemm64_kernel(
    const float* __restrict__ X, const int* __restrict__ idx,
    const float* __restrict__ W, const float* __restrict__ bias,
    void* __restrict__ Yv, ushort_t* __restrict__ Y2, int R, int out_mode)
{
    gemm64_body(X, idx, W, bias, Yv, Y2, R, out_mode, blockIdx.x);
}

// ---------------------------------------------------------------------------
// prep: ONE launch (re-fused, round-1 structure: measured 57us vs ~65 split).
// Blocks 0..10: small rel/qr gemms. Rest interleaves hsWs-gemm blocks with
// deg/rank/epack blocks (Bresenham). Deg counters sharded 8x by edge-chunk.
// epack[e] = (sub|rel<<17, obj|r_idx<<17).
// ---------------------------------------------------------------------------
#define G1 ((N_NODE + 63) / 64)            // 1563
#define G2 ((NVOCAB + 63) / 64)            // 7
#define G3 (NB / 64)                       // 4
#define GSMALL (G2 + G3)                   // 11
#define GD8 ((N_EDGE + EPB - 1) / EPB)     // 489
#define PREP_T (G1 + GD8)                  // 2052
#define PREP_GRID (GSMALL + PREP_T)

__global__ __launch_bounds__(256) void prep_kernel(
    const float* __restrict__ hidden,
    const float* __restrict__ rela,
    const int*   __restrict__ q_rel,
    const ushort_t* __restrict__ wsp,   // pre-split weights
    const float* __restrict__ Wqr_b,
    ushort_t* __restrict__ hsWs,
    ushort_t* __restrict__ hidb,
    ushort_t* __restrict__ rel_preb,
    ushort_t* __restrict__ relab,
    ushort_t* __restrict__ qr_preb,
    const int* __restrict__ edges,
    int* __restrict__ deg8,        // [8][N_NODE], pre-zeroed by init
    int* __restrict__ rank,
    int2* __restrict__ epack)
{
    int b = blockIdx.x;
    if (b < G2) {
        gemm64p_body(rela, nullptr, wsp + 1 * 8192, wsp + 1 * 8192 + 4096,
                     nullptr, rel_preb, relab, NVOCAB, 3, b);
    } else if (b < GSMALL) {
        gemm64p_body(rela, q_rel, wsp + 2 * 8192, wsp + 2 * 8192 + 4096,
                     Wqr_b, qr_preb, nullptr, NB, 2, b - G2);
    } else {
        int bp = b - GSMALL;
        int prior = (int)(((long)bp * GD8) / PREP_T);
        int nxt   = (int)(((long)(bp + 1) * GD8) / PREP_T);
        if (nxt > prior) {
            int base = prior * EPB + threadIdx.x;
            #pragma unroll
            for (int k = 0; k < 8; ++k) {
                int e = base + k * 256;
                if (e < N_EDGE) {
                    int2 ab = *(const int2*)(edges + (size_t)e * 6);      // (r_idx,0)
                    int2 cd = *(const int2*)(edges + (size_t)e * 6 + 2);  // (rel,0)
                    int2 ef = *(const int2*)(edges + (size_t)e * 6 + 4);  // (sub,obj)
                    epack[e] = make_int2(ef.x | (cd.x << 17), ef.y | (ab.x << 17));
                    int s = (e >> 11) & (NSHARD - 1);
                    rank[e] = atomicAdd(&deg8[s * N_NODE + ef.y], 1);
                }
            }
        } else {
            gemm64p_body(hidden, nullptr, wsp, wsp + 4096,
                         nullptr, hsWs, hidb, N_NODE, 3, bp - prior);
        }
    }
}

// ---------------------------------------------------------------------------
// CSR scan: scan1 produces raw per-chunk sums; scan3 redundantly reduces the
// (98) raw partials in LDS per block (scan2 folded in), then chunk-scans and
// rewrites deg8 into per-shard slot bases.
// ---------------------------------------------------------------------------
__global__ __launch_bounds__(SCAN_B) void scan1_kernel(const int* __restrict__ deg8,
                                                       int* __restrict__ partial)
{
    __shared__ int s[SCAN_B];
    int g = blockIdx.x * SCAN_B + threadIdx.x;
    int tot = 0;
    if (g < N_NODE)
        #pragma unroll
        for (int k = 0; k < NSHARD; ++k) tot += deg8[k * N_NODE + g];
    s[threadIdx.x] = tot;
    __syncthreads();
    for (int off = SCAN_B / 2; off; off >>= 1) {
        if (threadIdx.x < off) s[threadIdx.x] += s[threadIdx.x + off];
        __syncthreads();
    }
    if (threadIdx.x == 0) partial[blockIdx.x] = s[0];
}

__global__ __launch_bounds__(SCAN_B) void scan3_kernel(int* __restrict__ deg8,
                                                       const int* __restrict__ partial,
                                                       int* __restrict__ offs)
{
    __shared__ int s[SCAN_B];
    __shared__ int pbase_s;
    // inline scan2: base = sum of raw partial[k], k < blockIdx.x
    int pb = (threadIdx.x < (int)blockIdx.x) ? partial[threadIdx.x] : 0;
    s[threadIdx.x] = pb;
    __syncthreads();
    for (int off = SCAN_B / 2; off; off >>= 1) {
        if (threadIdx.x < off) s[threadIdx.x] += s[threadIdx.x + off];
        __syncthreads();
    }
    if (threadIdx.x == 0) pbase_s = s[0];
    __syncthreads();
    int pbase = pbase_s;
    __syncthreads();

    int g = blockIdx.x * SCAN_B + threadIdx.x;
    int d[NSHARD];
    int tot = 0;
    if (g < N_NODE) {
        #pragma unroll
        for (int k = 0; k < NSHARD; ++k) { d[k] = deg8[k * N_NODE + g]; tot += d[k]; }
    }
    s[threadIdx.x] = tot;
    __syncthreads();
    for (int off = 1; off < SCAN_B; off <<= 1) {
        int add = ((int)threadIdx.x >= off) ? s[threadIdx.x - off] : 0;
        __syncthreads();
        s[threadIdx.x] += add;
        __syncthreads();
    }
    if (g < N_NODE) {
        int incl = pbase + s[threadIdx.x];
        offs[g + 1] = incl;
        if (g == 0) offs[0] = 0;
        int run = incl - tot;                     // = offs[g]
        #pragma unroll
        for (int k = 0; k < NSHARD; ++k) { deg8[k * N_NODE + g] = run; run += d[k]; }
    }
}

// ---------------------------------------------------------------------------
// alpha + scatter: reads only epack (8B coalesced) + rank + bf16 tables.
// Quarter-wave, 4 edges/quarter, 64 edges/block. slot = base8[shard][obj]+rank.
// Sentinel pad now 32 slots (agg reads 16/iter with prefetch).
// ---------------------------------------------------------------------------
__global__ __launch_bounds__(256) void alpha_scatter_kernel(
    const int2*     __restrict__ epack,
    const int*      __restrict__ rank,
    const int*      __restrict__ base8,     // deg8 transformed by scan3
    const ushort_t* __restrict__ hsWs,
    const ushort_t* __restrict__ rel_preb,
    const ushort_t* __restrict__ qr_preb,
    const float*    __restrict__ wattn,
    int2*           __restrict__ csr2)
{
    int tid = blockIdx.x * 256 + threadIdx.x;
    if (tid < 32) csr2[N_EDGE + tid] = make_int2(0, 0);

    int wave = threadIdx.x >> 6;
    int lane = threadIdx.x & 63;
    int q    = lane >> 4;
    int l    = lane & 15;
    int f0   = l * 4;
    int e0   = (blockIdx.x * 4 + wave) * 16 + q * 4;

    float4 wa = *(const float4*)(wattn + f0);

    int   sub[4], rl[4], ob[4];
    float t[4];
    #pragma unroll
    for (int j = 0; j < 4; ++j) {
        int e = e0 + j;
        int2 ep = epack[e];
        sub[j] = ep.x & 0x1FFFF;
        rl[j]  = (int)((unsigned)ep.x >> 17);
        ob[j]  = ep.y & 0x1FFFF;
        int ri = (int)((unsigned)ep.y >> 17);

        uint2 uh = *(const uint2*)(hsWs     + (size_t)sub[j] * DIM + f0);
        uint2 ur = *(const uint2*)(rel_preb + (size_t)rl[j]  * DIM + f0);
        uint2 uq = *(const uint2*)(qr_preb  + (size_t)ri     * DIM + f0);

        float tt =  fmaxf(bflo(uh.x) + bflo(ur.x) + bflo(uq.x), 0.f) * wa.x;
        tt = fmaf(fmaxf(bfhi(uh.x) + bfhi(ur.x) + bfhi(uq.x), 0.f), wa.y, tt);
        tt = fmaf(fmaxf(bflo(uh.y) + bflo(ur.y) + bflo(uq.y), 0.f), wa.z, tt);
        tt = fmaf(fmaxf(bfhi(uh.y) + bfhi(ur.y) + bfhi(uq.y), 0.f), wa.w, tt);
        t[j] = tt;
    }
    #pragma unroll
    for (int j = 0; j < 4; ++j) {
        t[j] += __shfl_xor(t[j], 1);
        t[j] += __shfl_xor(t[j], 2);
        t[j] += __shfl_xor(t[j], 4);
        t[j] += __shfl_xor(t[j], 8);
    }

    if (l < 4) {
        int j = l;
        int e = e0 + j;
        int sh = (e0 >> 11) & (NSHARD - 1);      // all 4 edges share a 2048-chunk
        float alpha = 1.0f / (1.0f + __expf(-t[j]));
        int slot = base8[sh * N_NODE + ob[j]] + rank[e];
        csr2[slot] = make_int2(sub[j],
            (int)(((unsigned)rl[j] << 16) | f2h(alpha)));
    }
}

// ---------------------------------------------------------------------------
// Aggregation v7: persistent waves, 16 edges/iter (2x MLP of v6), sentinel-
// padded csr2 (no min clamps), 32-bit gather addressing, bf16 output.
// ---------------------------------------------------------------------------
__global__ __launch_bounds__(256) void agg_kernel(
    const int2*     __restrict__ csr2,
    const int*      __restrict__ offs,
    const ushort_t* __restrict__ hB,
    const ushort_t* __restrict__ relab,
    ushort_t* __restrict__ aggb)         // bf16 [N_NODE][64]
{
    int lane = threadIdx.x & 63;
    int q    = lane >> 4;
    int l    = lane & 15;
    int f0   = l * 4;
    int wv = __builtin_amdgcn_readfirstlane((blockIdx.x * blockDim.x + threadIdx.x) >> 6);

    int i   = offs[wv];
    int end = offs[wv + 1];
    for (int n = wv; n < N_NODE; n += AGG_WAVES) {
        int nn = n + AGG_WAVES;
        int ni = 0, ne = 0;
        if (nn < N_NODE) { ni = offs[nn]; ne = offs[nn + 1]; }

        float4 acc = make_float4(0.f, 0.f, 0.f, 0.f);
        int2 e[4];
        #pragma unroll
        for (int j = 0; j < 4; ++j) e[j] = csr2[i + 4 * j + q];
        while (i < end) {
            int2 p[4];
            #pragma unroll
            for (int j = 0; j < 4; ++j) p[j] = csr2[i + 16 + 4 * j + q];

            // issue all 8 gathers before consuming
            uint2 uh[4], ur[4];
            #pragma unroll
            for (int j = 0; j < 4; ++j) {
                unsigned ey = (unsigned)e[j].y;
                uh[j] = *(const uint2*)(hB    + (((unsigned)e[j].x) << 6) + f0);
                ur[j] = *(const uint2*)(relab + ((ey >> 16) << 6) + f0);
            }
            #pragma unroll
            for (int j = 0; j < 4; ++j) {
                unsigned ey = (unsigned)e[j].y;
                float v  = (i + 4 * j + q < end) ? 1.0f : 0.0f;
                float al = v * h2f(ey & 0xFFFFu);
                acc.x = fmaf(al, bflo(uh[j].x) + bflo(ur[j].x), acc.x);
                acc.y = fmaf(al, bfhi(uh[j].x) + bfhi(ur[j].x), acc.y);
                acc.z = fmaf(al, bflo(uh[j].y) + bflo(ur[j].y), acc.z);
                acc.w = fmaf(al, bfhi(uh[j].y) + bfhi(ur[j].y), acc.w);
            }
            #pragma unroll
            for (int j = 0; j < 4; ++j) e[j] = p[j];
            i += 16;
        }

        acc.x += __shfl_xor(acc.x, 16); acc.x += __shfl_xor(acc.x, 32);
        acc.y += __shfl_xor(acc.y, 16); acc.y += __shfl_xor(acc.y, 32);
        acc.z += __shfl_xor(acc.z, 16); acc.z += __shfl_xor(acc.z, 32);
        acc.w += __shfl_xor(acc.w, 16); acc.w += __shfl_xor(acc.w, 32);
        if (q == 0) {
            uint2 o;
            o.x = (unsigned)f2bf_rne(acc.x) | ((unsigned)f2bf_rne(acc.y) << 16);
            o.y = (unsigned)f2bf_rne(acc.z) | ((unsigned)f2bf_rne(acc.w) << 16);
            *(uint2*)(aggb + (((unsigned)n) << 6) + f0) = o;
        }

        i = ni; end = ne;
    }
}

// ---------------------------------------------------------------------------
// Fallback (ws too small): wave-per-edge atomic kernel, bf16 tables.
// ---------------------------------------------------------------------------
__global__ __launch_bounds__(256) void edge_kernel(
    const int*      __restrict__ edges,
    const ushort_t* __restrict__ hB,
    const ushort_t* __restrict__ relab,
    const ushort_t* __restrict__ hsWs,
    const ushort_t* __restrict__ rel_preb,
    const ushort_t* __restrict__ qr_preb,
    const float*    __restrict__ wattn,
    float* __restrict__ out)
{
    int e = (blockIdx.x * blockDim.x + threadIdx.x) >> 6;
    if (e >= N_EDGE) return;
    int lane = threadIdx.x & 63;
    int r_i = edges[e * 6 + 0];
    int rl  = edges[e * 6 + 2];
    int sb  = edges[e * 6 + 4];
    int ob  = edges[e * 6 + 5];
    float hs = __uint_as_float(((unsigned)hB[(size_t)sb * DIM + lane]) << 16);
    float hr = __uint_as_float(((unsigned)relab[(size_t)rl * DIM + lane]) << 16);
    float p1 = __uint_as_float(((unsigned)hsWs[(size_t)sb * DIM + lane]) << 16);
    float p2 = __uint_as_float(((unsigned)rel_preb[(size_t)rl * DIM + lane]) << 16);
    float p3 = __uint_as_float(((unsigned)qr_preb[(size_t)r_i * DIM + lane]) << 16);
    float t = wattn[lane] * fmaxf(p1 + p2 + p3, 0.0f);
    #pragma unroll
    for (int off = 32; off; off >>= 1) t += __shfl_xor(t, off);
    float alpha = 1.0f / (1.0f + __expf(-t));
    atomicAdd(&out[(size_t)ob * DIM + lane], (hs + hr) * alpha);
}

extern "C" void kernel_launch(void* const* d_in, const int* in_sizes, int n_in,
                              void* d_out, int out_size, void* d_ws, size_t ws_size,
                              hipStream_t stream)
{
    const float* hidden = (const float*)d_in[0];
    const int*   q_rel  = (const int*)  d_in[1];
    const int*   edges  = (const int*)  d_in[2];
    const float* rela   = (const float*)d_in[3];
    const float* Ws     = (const float*)d_in[4];
    const float* Wr     = (const float*)d_in[5];
    const float* Wqr    = (const float*)d_in[6];
    const float* Wqr_b  = (const float*)d_in[7];
    const float* Wattn  = (const float*)d_in[8];
    const float* Wh     = (const float*)d_in[9];
    float* out = (float*)d_out;

    // ---- workspace layout ----
    ushort_t* qr_preb  = (ushort_t*)d_ws;                 // 256*64 bf16
    ushort_t* rel_preb = qr_preb + NB * DIM;              // 401*64 bf16
    ushort_t* relab    = rel_preb + NVOCAB * DIM;         // 401*64 bf16
    ushort_t* hsWs     = relab + NVOCAB * DIM;            // 100000*64 bf16
    ushort_t* hidb     = hsWs + (size_t)N_NODE * DIM;     // 100000*64 bf16
    int2* epack  = (int2*)(((uintptr_t)(hidb + (size_t)N_NODE * DIM) + 15) & ~(uintptr_t)15);
    int*  rank   = (int*)(epack + N_EDGE);                // N_EDGE
    int*  deg8   = rank + N_EDGE;                         // 8*N_NODE
    int*  offs   = deg8 + NSHARD * N_NODE;                // N_NODE+1
    int*  partial= offs + (N_NODE + 1);                   // 128
    int2* csr2   = (int2*)(((uintptr_t)(partial + 128) + 15) & ~(uintptr_t)15);
    ushort_t* wsp = (ushort_t*)(csr2 + N_EDGE + 32);      // 4*2*4096 bf16 (64KB)
    size_t csr_need = ((char*)(wsp + 4 * 8192)) - (char*)d_ws;
    bool use_csr = ws_size >= csr_need;
    // aggb aliases the dead epack/rank/deg8 region (15.2MB >= 12.8MB needed);
    // epack/rank/deg8 are dead after alpha_scatter; csr2/offs/wsp stay intact.
    ushort_t* aggb = (ushort_t*)epack;

    if (use_csr) {
        init_kernel<<<INIT_GRID, 256, 0, stream>>>(Ws, Wr, Wqr, Wh, wsp, deg8);
        prep_kernel<<<PREP_GRID, 256, 0, stream>>>(
            hidden, rela, q_rel, wsp, Wqr_b,
            hsWs, hidb, rel_preb, relab, qr_preb, edges, deg8, rank, epack);
        scan1_kernel<<<NCHUNK, SCAN_B, 0, stream>>>(deg8, partial);
        scan3_kernel<<<NCHUNK, SCAN_B, 0, stream>>>(deg8, partial, offs);
        alpha_scatter_kernel<<<N_EDGE / 64, 256, 0, stream>>>(
            epack, rank, deg8, hsWs, rel_preb, qr_preb, Wattn, csr2);
        agg_kernel<<<AGG_WAVES / 4, 256, 0, stream>>>(csr2, offs, hidb, relab, aggb);
        gemm64p_bf16A_kernel<<<(N_NODE + 63) / 64, 256, 0, stream>>>(
            aggb, wsp + 3 * 8192, wsp + 3 * 8192 + 4096, out, N_NODE);
    } else {
        gemm64_kernel<<<(NVOCAB + 63) / 64, 256, 0, stream>>>(
            rela, nullptr, Wr, nullptr, rel_preb, relab, NVOCAB, 3);
        gemm64_kernel<<<(NB + 63) / 64, 256, 0, stream>>>(
            rela, q_rel, Wqr, Wqr_b, qr_preb, nullptr, NB, 2);
        gemm64_kernel<<<(N_NODE + 63) / 64, 256, 0, stream>>>(
            hidden, nullptr, Ws, nullptr, hsWs, hidb, N_NODE, 3);
        hipMemsetAsync(d_out, 0, (size_t)N_NODE * DIM * sizeof(float), stream);
        edge_kernel<<<(N_EDGE + 3) / 4, 256, 0, stream>>>(
            edges, hidb, relab, hsWs, rel_preb, qr_preb, Wattn, out);
        gemm64_kernel<<<(N_NODE + 63) / 64, 256, 0, stream>>>(
            out, nullptr, Wh, nullptr, out, nullptr, N_NODE, 1);
    }
}